// Round 27
// baseline (73.189 us; speedup 1.0000x reference)
//
#include <hip/hip_runtime.h>
#include <hip/hip_bf16.h>

#define NPOS 1600
#define HEADS 8
#define KEY_DIM 16
#define HEAD_DIM 32
#define DIM 256
#define QKV_DIM 512
#define SSTRIDE 1616   // shorts; 3232B = 32 mod 128 -> rows start in rotating bank quadrants

typedef __attribute__((ext_vector_type(8))) short short8;
typedef __attribute__((ext_vector_type(4))) short short4v;
typedef __attribute__((ext_vector_type(4))) float f32x4;

// RNE f32->bf16 via the intrinsic cast (enables v_cvt_pk_bf16_f32 fusion).
__device__ __forceinline__ unsigned short f2b(float f) {
  __hip_bfloat16 h = __float2bfloat16(f);
  return *reinterpret_cast<unsigned short*>(&h);
}
__device__ __forceinline__ float b2f(unsigned short h) {
  return __uint_as_float(((unsigned)h) << 16);
}
// bank-spread involution (byte-bits 4..6 only): preserves aligned 8B/16B blocks.
__device__ __forceinline__ int smask(int row) {
  return ((row & 7) << 4) ^ ((row & 12) << 3);
}

// ---------------- kernel B: convert weights to bf16 ----------------
__global__ __launch_bounds__(256) void convw_kernel(
    const float* __restrict__ wq, const float* __restrict__ wp,
    unsigned short* __restrict__ wqb, unsigned short* __restrict__ wpb) {
  int idx = (blockIdx.x * 256 + threadIdx.x) * 8;
  #pragma unroll
  for (int i = 0; i < 8; ++i) {
    int e = idx + i;
    if (e < QKV_DIM * DIM) wqb[e] = f2b(wq[e]);
    else wpb[e - QKV_DIM * DIM] = f2b(wp[e - QKV_DIM * DIM]);
  }
}

// ---------------- kernel 1: qkv via MFMA, x staged+transposed in LDS ----------------
__global__ __launch_bounds__(256) void qkv_mfma(
    const float* __restrict__ x, const unsigned short* __restrict__ wqb,
    const float* __restrict__ bq, unsigned short* __restrict__ qT16,
    unsigned short* __restrict__ kT16, unsigned short* __restrict__ vb16) {
  __shared__ unsigned short xs[64 * 264];  // [n_local][c], stride 264 elems
  int t = threadIdx.x, lane = t & 63, w = t >> 6;
  int l15 = lane & 15, lg = lane >> 4;
  int n0 = blockIdx.x * 64, b = blockIdx.z;
  int hh = blockIdx.y;
  int cow = hh * 64 + w * 16;

  // stage: transpose x[c][n0..n0+63] fp32 -> xs[n][c] bf16
  {
    int crow_base = t >> 2, colb = (t & 3) * 16;
    #pragma unroll
    for (int cc = 0; cc < 4; ++cc) {
      int c_row = cc * 64 + crow_base;
      const float* src = x + ((size_t)(b * DIM + c_row)) * NPOS + n0 + colb;
      float4 v0 = *(const float4*)(src);
      float4 v1 = *(const float4*)(src + 4);
      float4 v2 = *(const float4*)(src + 8);
      float4 v3 = *(const float4*)(src + 12);
      float vv[16] = {v0.x, v0.y, v0.z, v0.w, v1.x, v1.y, v1.z, v1.w,
                      v2.x, v2.y, v2.z, v2.w, v3.x, v3.y, v3.z, v3.w};
      #pragma unroll
      for (int i = 0; i < 16; ++i)
        xs[(colb + i) * 264 + c_row] = f2b(vv[i]);
    }
  }
  __syncthreads();

  short8 af[8];
  #pragma unroll
  for (int ks = 0; ks < 8; ++ks)
    af[ks] = *(const short8*)(wqb + (size_t)(cow + l15) * DIM + ks * 32 + lg * 8);
  f32x4 acc[4];
  #pragma unroll
  for (int sub = 0; sub < 4; ++sub) {
    int nl = sub * 16 + l15;
    const unsigned short* xb = xs + nl * 264 + lg * 8;
    f32x4 a = {0.f, 0.f, 0.f, 0.f};
    #pragma unroll
    for (int ks = 0; ks < 8; ++ks)
      a = __builtin_amdgcn_mfma_f32_16x16x32_bf16(af[ks], *(const short8*)(xb + ks * 32), a, 0, 0, 0);
    acc[sub] = a;
  }
  int bh = b * HEADS + hh;
  if (w < 2) {
    unsigned short* dst = w ? kT16 : qT16;
    int cobase = cow + lg * 4;
    #pragma unroll
    for (int sub = 0; sub < 4; ++sub) {
      int n = n0 + sub * 16 + l15;
      short4v o;
      #pragma unroll
      for (int r = 0; r < 4; ++r) o[r] = (short)f2b(acc[sub][r] + bq[cobase + r]);
      *(short4v*)(dst + ((size_t)bh * NPOS + n) * KEY_DIM + lg * 4) = o;
    }
  } else {
    #pragma unroll
    for (int sub = 0; sub < 4; ++sub) {
      #pragma unroll
      for (int r = 0; r < 4; ++r) {
        int d = (w - 2) * 16 + lg * 4 + r;
        int n = n0 + sub * 16 + l15;
        float val = acc[sub][r] + bq[cow + lg * 4 + r];
        vb16[((size_t)(b * DIM + hh * HEAD_DIM + d)) * NPOS + n] = f2b(val);
      }
    }
  }
}

// ---------------- kernel 2: row norms of q,k + fold temp*invq*invk into qT16 ----------------
__global__ __launch_bounds__(256) void normscale_kernel(
    unsigned short* __restrict__ qT16, const unsigned short* __restrict__ kT16,
    const float* __restrict__ temp) {
  __shared__ float lred[4][32];
  __shared__ float scal[16];
  int bh = blockIdx.x;
  int t = threadIdx.x, lane = t & 63, w = t >> 6;
  float sq[16], sk[16];
  #pragma unroll
  for (int i = 0; i < 16; ++i) { sq[i] = 0.f; sk[i] = 0.f; }
  for (int j = 0; j < 7; ++j) {
    int n = t + 256 * j;
    if (n < NPOS) {
      size_t base = ((size_t)bh * NPOS + n) * KEY_DIM;
      short8 a0 = *(const short8*)(qT16 + base);
      short8 a1 = *(const short8*)(qT16 + base + 8);
      short8 b0 = *(const short8*)(kT16 + base);
      short8 b1 = *(const short8*)(kT16 + base + 8);
      #pragma unroll
      for (int e = 0; e < 8; ++e) {
        float v0 = b2f((unsigned short)a0[e]); sq[e] = fmaf(v0, v0, sq[e]);
        float v1 = b2f((unsigned short)a1[e]); sq[8 + e] = fmaf(v1, v1, sq[8 + e]);
        float u0 = b2f((unsigned short)b0[e]); sk[e] = fmaf(u0, u0, sk[e]);
        float u1 = b2f((unsigned short)b1[e]); sk[8 + e] = fmaf(u1, u1, sk[8 + e]);
      }
    }
  }
  #pragma unroll
  for (int o = 32; o; o >>= 1) {
    #pragma unroll
    for (int i = 0; i < 16; ++i) {
      sq[i] += __shfl_xor(sq[i], o, 64);
      sk[i] += __shfl_xor(sk[i], o, 64);
    }
  }
  if (lane == 0) {
    #pragma unroll
    for (int i = 0; i < 16; ++i) { lred[w][i] = sq[i]; lred[w][16 + i] = sk[i]; }
  }
  __syncthreads();
  if (t < 16) {
    float a = 0.f, bb = 0.f;
    #pragma unroll
    for (int wv = 0; wv < 4; ++wv) { a += lred[wv][t]; bb += lred[wv][16 + t]; }
    float invq = 1.0f / fmaxf(sqrtf(a), 1e-12f);
    float invk = 1.0f / fmaxf(sqrtf(bb), 1e-12f);
    scal[t] = temp[bh & 7] * invq * invk;
  }
  __syncthreads();
  float sc[16];
  #pragma unroll
  for (int i = 0; i < 16; ++i) sc[i] = scal[i];
  for (int j = 0; j < 7; ++j) {
    int n = t + 256 * j;
    if (n < NPOS) {
      size_t base = ((size_t)bh * NPOS + n) * KEY_DIM;
      short8 a0 = *(const short8*)(qT16 + base);
      short8 a1 = *(const short8*)(qT16 + base + 8);
      short8 o0, o1;
      #pragma unroll
      for (int e = 0; e < 8; ++e) {
        o0[e] = (short)f2b(b2f((unsigned short)a0[e]) * sc[e]);
        o1[e] = (short)f2b(b2f((unsigned short)a1[e]) * sc[8 + e]);
      }
      *(short8*)(qT16 + base) = o0;
      *(short8*)(qT16 + base + 8) = o1;
    }
  }
}

// ---------------- kernel 3: fused attention; swapped QK^T; stride-1616 S tile ----------------
__global__ __launch_bounds__(1024) void attn_kernel(
    const unsigned short* __restrict__ qT16, const unsigned short* __restrict__ kT16,
    const unsigned short* __restrict__ vb16,
    const float* __restrict__ supp, const float* __restrict__ wpe,
    const float* __restrict__ bpe, unsigned short* __restrict__ ybT) {
  __shared__ __align__(128) unsigned short s16[16 * SSTRIDE]; // 51712 B, [qrow][m] bf16
  __shared__ unsigned short redb[16][2][16][18];              // PV partials bf16, padded
  __shared__ float pstat[2][16][16];                          // [stat][qrow][wave]
  __shared__ float dpart[16][16];                             // denom partials [n][wave]
  int t = threadIdx.x, lane = t & 63, w = t >> 6;
  int l15 = lane & 15, lg = lane >> 4;
  int n0 = blockIdx.x * 16;
  int h = blockIdx.y, b = blockIdx.z;
  int bh = b * HEADS + h;
  float sgm = 1.0f / (1.0f + __expf(-supp[0]));

  // ---- phase 1: S^T = K*Q^T via mfma(K_frag, Q_frag): lane holds 4 consecutive m
  //      for qrow=l15 -> single b64 store; stats lane-local per qrow. ----
  {
    short8 qa = {0, 0, 0, 0, 0, 0, 0, 0};
    if (lane < 32)
      qa = *(const short8*)(qT16 + ((size_t)bh * NPOS + n0 + l15) * KEY_DIM + lg * 8);
    float ssum = 0.f, ssq = 0.f;
    for (int mt = w; mt < NPOS / 16; mt += 16) {
      int m0 = mt * 16;
      short8 kb = {0, 0, 0, 0, 0, 0, 0, 0};
      if (lane < 32)
        kb = *(const short8*)(kT16 + ((size_t)bh * NPOS + m0 + l15) * KEY_DIM + lg * 8);
      f32x4 acc = {0.f, 0.f, 0.f, 0.f};
      acc = __builtin_amdgcn_mfma_f32_16x16x32_bf16(kb, qa, acc, 0, 0, 0);
      short4v o;
      #pragma unroll
      for (int r = 0; r < 4; ++r) {
        float v = acc[r];
        o[r] = (short)f2b(v);
        ssum += v;
        ssq = fmaf(v, v, ssq);
      }
      int byteoff = (l15 * (SSTRIDE * 2) + (m0 + lg * 4) * 2) ^ smask(l15);
      *(short4v*)(s16 + (byteoff >> 1)) = o;
    }
    ssum += __shfl_xor(ssum, 16, 64); ssq += __shfl_xor(ssq, 16, 64);
    ssum += __shfl_xor(ssum, 32, 64); ssq += __shfl_xor(ssq, 32, 64);
    if (lane < 16) {
      pstat[0][l15][w] = ssum;
      pstat[1][l15][w] = ssq;
    }
  }
  __syncthreads();

  // ---- phase 2: wave w owns m-residue w; computes pb once, both d-tiles ----
  {
    float su = 0.f, sq = 0.f;
    #pragma unroll
    for (int j = 0; j < 4; ++j) {
      su += pstat[0][l15][lg + 4 * j];
      sq += pstat[1][l15][lg + 4 * j];
    }
    su += __shfl_xor(su, 16, 64); sq += __shfl_xor(sq, 16, 64);
    su += __shfl_xor(su, 32, 64); sq += __shfl_xor(sq, 32, 64);
    float mu = su * (1.0f / NPOS);
    float var = fmaxf(sq * (1.0f / NPOS) - mu * mu, 0.0f);
    float thr_lane = mu - 0.84162123f * sqrtf(var);   // 20th pctile (rank 320/1600)

    const unsigned short* vrow0 = vb16 + ((size_t)(b * DIM + h * HEAD_DIM + l15)) * NPOS;
    const unsigned short* vrow1 = vrow0 + (size_t)16 * NPOS;
    f32x4 acc0 = {0.f, 0.f, 0.f, 0.f};
    f32x4 acc1 = {0.f, 0.f, 0.f, 0.f};
    float psum = 0.0f;
    for (int c = w; c < NPOS / 32; c += 16) {
      int m0 = c * 32 + lg * 8;
      short8 va0 = *(const short8*)(vrow0 + m0);
      short8 va1 = *(const short8*)(vrow1 + m0);
      int byteoff = (l15 * (SSTRIDE * 2) + m0 * 2) ^ smask(l15);
      short8 sv = *(const short8*)(s16 + (byteoff >> 1));
      short8 pb;
      #pragma unroll
      for (int e = 0; e < 8; ++e) {
        float v = b2f((unsigned short)sv[e]);
        float p = (v >= thr_lane) ? v : v * sgm;
        float ex = 1.0f + p;
        psum += ex;
        pb[e] = (short)f2b(ex);
      }
      acc0 = __builtin_amdgcn_mfma_f32_16x16x32_bf16(va0, pb, acc0, 0, 0, 0);
      acc1 = __builtin_amdgcn_mfma_f32_16x16x32_bf16(va1, pb, acc1, 0, 0, 0);
    }
    psum += __shfl_xor(psum, 16, 64);
    psum += __shfl_xor(psum, 32, 64);
    if (lane < 16) dpart[l15][w] = psum;
    #pragma unroll
    for (int r = 0; r < 4; ++r) {
      redb[w][0][lg * 4 + r][l15] = f2b(acc0[r]);
      redb[w][1][lg * 4 + r][l15] = f2b(acc1[r]);
    }
  }
  __syncthreads();

  // ---- phase 3: 16-way cross-wave reduce + normalize + fused pe conv + bf16 store ----
  if (t < 512) {
    int tl = t >> 8, i = (t >> 4) & 15, j = t & 15;
    float v = 0.0f;
    #pragma unroll
    for (int s = 0; s < 16; ++s) v += b2f(redb[s][tl][i][j]);
    float den = 0.0f;
    #pragma unroll
    for (int s = 0; s < 16; ++s) den += dpart[j][s];
    int c = h * HEAD_DIM + tl * 16 + i;
    int n = n0 + j;
    float o = v / den;
    int py = n / 40, px = n - py * 40;
    const unsigned short* vp = vb16 + (size_t)(b * DIM + c) * NPOS;
    const float* w9 = wpe + c * 9;
    float acc2 = bpe[c];
    #pragma unroll
    for (int dy = -1; dy <= 1; ++dy) {
      int iy = py + dy;
      if (iy < 0 || iy > 39) continue;
      #pragma unroll
      for (int dx = -1; dx <= 1; ++dx) {
        int ix = px + dx;
        if (ix < 0 || ix > 39) continue;
        acc2 = fmaf(b2f(vp[iy * 40 + ix]), w9[(dy + 1) * 3 + (dx + 1)], acc2);
      }
    }
    o += acc2;
    ybT[((size_t)(b * NPOS + n)) * DIM + c] = f2b(o);
  }
}

// ---------------- kernel 5: proj via MFMA -> fp32 out ----------------
__global__ __launch_bounds__(256) void proj_mfma(
    const unsigned short* __restrict__ ybT, const unsigned short* __restrict__ wpb,
    const float* __restrict__ bp, float* __restrict__ out) {
  int t = threadIdx.x, lane = t & 63, w = t >> 6;
  int l15 = lane & 15, lg = lane >> 4;
  int n0 = blockIdx.x * 64, co0 = blockIdx.y * 64, b = blockIdx.z;
  int cow = co0 + w * 16;
  short8 af[8];
  #pragma unroll
  for (int ks = 0; ks < 8; ++ks)
    af[ks] = *(const short8*)(wpb + (size_t)(cow + l15) * DIM + ks * 32 + lg * 8);
  f32x4 acc[4];
  #pragma unroll
  for (int sub = 0; sub < 4; ++sub) {
    int n = n0 + sub * 16 + l15;
    const unsigned short* yb = ybT + (size_t)(b * NPOS + n) * DIM + lg * 8;
    f32x4 a = {0.f, 0.f, 0.f, 0.f};
    #pragma unroll
    for (int ks = 0; ks < 8; ++ks)
      a = __builtin_amdgcn_mfma_f32_16x16x32_bf16(af[ks], *(const short8*)(yb + ks * 32), a, 0, 0, 0);
    acc[sub] = a;
  }
  #pragma unroll
  for (int sub = 0; sub < 4; ++sub) {
    #pragma unroll
    for (int r = 0; r < 4; ++r) {
      int co = cow + lg * 4 + r;
      int n = n0 + sub * 16 + l15;
      out[((size_t)(b * DIM + co)) * NPOS + n] = acc[sub][r] + bp[co];
    }
  }
}

extern "C" void kernel_launch(void* const* d_in, const int* in_sizes, int n_in,
                              void* d_out, int out_size, void* d_ws, size_t ws_size,
                              hipStream_t stream) {
  (void)in_sizes; (void)n_in; (void)out_size; (void)ws_size;
  const float* x = (const float*)d_in[0];
  const float* w_qkv = (const float*)d_in[1];
  const float* b_qkv = (const float*)d_in[2];
  const float* w_proj = (const float*)d_in[3];
  const float* b_proj = (const float*)d_in[4];
  const float* w_pe = (const float*)d_in[5];
  const float* b_pe = (const float*)d_in[6];
  const float* temperature = (const float*)d_in[7];
  const float* supp = (const float*)d_in[8];

  unsigned short* wsu = (unsigned short*)d_ws;
  unsigned short* vb16 = wsu;                           // 819200 bf16
  unsigned short* qT16 = vb16 + 819200;                 // 409600
  unsigned short* kT16 = qT16 + 409600;                 // 409600
  unsigned short* ybT  = kT16 + 409600;                 // 819200
  unsigned short* wqb  = ybT + 819200;                  // 131072
  unsigned short* wpb  = wqb + 131072;                  // 65536
  float* out = (float*)d_out;

  convw_kernel<<<dim3(96, 1, 1), 256, 0, stream>>>(w_qkv, w_proj, wqb, wpb);
  qkv_mfma<<<dim3(25, 8, 2), 256, 0, stream>>>(x, wqb, b_qkv, qT16, kT16, vb16);
  normscale_kernel<<<dim3(16), 256, 0, stream>>>(qT16, kT16, temperature);
  attn_kernel<<<dim3(NPOS / 16, HEADS, 2), 1024, 0, stream>>>(qT16, kT16, vb16, supp, w_pe, b_pe, ybT);
  proj_mfma<<<dim3(25, 4, 2), 256, 0, stream>>>(ybT, wpb, b_proj, out);
}

// Round 28
// 69.280 us; speedup vs baseline: 1.0564x; 1.0564x over previous
//
#include <hip/hip_runtime.h>
#include <hip/hip_bf16.h>

#define NPOS 1600
#define HEADS 8
#define KEY_DIM 16
#define HEAD_DIM 32
#define DIM 256
#define QKV_DIM 512
#define SSTRIDE 1600

typedef __attribute__((ext_vector_type(8))) short short8;
typedef __attribute__((ext_vector_type(4))) short short4v;
typedef __attribute__((ext_vector_type(4))) float f32x4;

__device__ __forceinline__ unsigned short f2b(float f) {
  __hip_bfloat16 h = __float2bfloat16(f);
  return *reinterpret_cast<unsigned short*>(&h);
}
__device__ __forceinline__ float b2f(unsigned short h) {
  return __uint_as_float(((unsigned)h) << 16);
}
// bank-spread involution (byte-bits 4..6 only): preserves aligned 8B/16B blocks.
__device__ __forceinline__ int smask(int row) {
  return ((row & 7) << 4) ^ ((row & 12) << 3);
}

// ---------------- kernel B: convert weights to bf16 + zero the sumsq buffer ----------------
__global__ __launch_bounds__(256) void convw_kernel(
    const float* __restrict__ wq, const float* __restrict__ wp,
    unsigned short* __restrict__ wqb, unsigned short* __restrict__ wpb,
    float* __restrict__ sqk) {
  if (blockIdx.x == 0) {
    sqk[threadIdx.x] = 0.0f;
    sqk[threadIdx.x + 256] = 0.0f;
  }
  int idx = (blockIdx.x * 256 + threadIdx.x) * 8;
  #pragma unroll
  for (int i = 0; i < 8; ++i) {
    int e = idx + i;
    if (e < QKV_DIM * DIM) wqb[e] = f2b(wq[e]);
    else wpb[e - QKV_DIM * DIM] = f2b(wp[e - QKV_DIM * DIM]);
  }
}

// ---------------- kernel 1: qkv via MFMA + fused q/k sumsq atomics ----------------
__global__ __launch_bounds__(256) void qkv_mfma(
    const float* __restrict__ x, const unsigned short* __restrict__ wqb,
    const float* __restrict__ bq, unsigned short* __restrict__ qT16,
    unsigned short* __restrict__ kT16, unsigned short* __restrict__ vb16,
    float* __restrict__ sqk) {
  __shared__ unsigned short xs[64 * 264];  // [n_local][c], stride 264 elems
  int t = threadIdx.x, lane = t & 63, w = t >> 6;
  int l15 = lane & 15, lg = lane >> 4;
  int n0 = blockIdx.x * 64, b = blockIdx.z;
  int hh = blockIdx.y;
  int cow = hh * 64 + w * 16;

  // stage: transpose x[c][n0..n0+63] fp32 -> xs[n][c] bf16
  {
    int crow_base = t >> 2, colb = (t & 3) * 16;
    #pragma unroll
    for (int cc = 0; cc < 4; ++cc) {
      int c_row = cc * 64 + crow_base;
      const float* src = x + ((size_t)(b * DIM + c_row)) * NPOS + n0 + colb;
      float4 v0 = *(const float4*)(src);
      float4 v1 = *(const float4*)(src + 4);
      float4 v2 = *(const float4*)(src + 8);
      float4 v3 = *(const float4*)(src + 12);
      float vv[16] = {v0.x, v0.y, v0.z, v0.w, v1.x, v1.y, v1.z, v1.w,
                      v2.x, v2.y, v2.z, v2.w, v3.x, v3.y, v3.z, v3.w};
      #pragma unroll
      for (int i = 0; i < 16; ++i)
        xs[(colb + i) * 264 + c_row] = f2b(vv[i]);
    }
  }
  __syncthreads();

  short8 af[8];
  #pragma unroll
  for (int ks = 0; ks < 8; ++ks)
    af[ks] = *(const short8*)(wqb + (size_t)(cow + l15) * DIM + ks * 32 + lg * 8);
  f32x4 acc[4];
  #pragma unroll
  for (int sub = 0; sub < 4; ++sub) {
    int nl = sub * 16 + l15;
    const unsigned short* xb = xs + nl * 264 + lg * 8;
    f32x4 a = {0.f, 0.f, 0.f, 0.f};
    #pragma unroll
    for (int ks = 0; ks < 8; ++ks)
      a = __builtin_amdgcn_mfma_f32_16x16x32_bf16(af[ks], *(const short8*)(xb + ks * 32), a, 0, 0, 0);
    acc[sub] = a;
  }
  int bh = b * HEADS + hh;
  if (w < 2) {
    unsigned short* dst = w ? kT16 : qT16;
    int cobase = cow + lg * 4;
    float ssq[4] = {0.f, 0.f, 0.f, 0.f};
    #pragma unroll
    for (int sub = 0; sub < 4; ++sub) {
      int n = n0 + sub * 16 + l15;
      short4v o;
      #pragma unroll
      for (int r = 0; r < 4; ++r) {
        float val = acc[sub][r] + bq[cobase + r];
        o[r] = (short)f2b(val);
        ssq[r] = fmaf(val, val, ssq[r]);
      }
      *(short4v*)(dst + ((size_t)bh * NPOS + n) * KEY_DIM + lg * 4) = o;
    }
    // reduce over the 16 n-lanes (l15), then one atomic per kk
    #pragma unroll
    for (int o2 = 1; o2 < 16; o2 <<= 1) {
      #pragma unroll
      for (int r = 0; r < 4; ++r) ssq[r] += __shfl_xor(ssq[r], o2, 64);
    }
    if (l15 == 0) {
      float* buf = sqk + (w ? 256 : 0) + bh * 16 + lg * 4;
      #pragma unroll
      for (int r = 0; r < 4; ++r) atomicAdd(&buf[r], ssq[r]);
    }
  } else {
    #pragma unroll
    for (int sub = 0; sub < 4; ++sub) {
      #pragma unroll
      for (int r = 0; r < 4; ++r) {
        int d = (w - 2) * 16 + lg * 4 + r;
        int n = n0 + sub * 16 + l15;
        float val = acc[sub][r] + bq[cow + lg * 4 + r];
        vb16[((size_t)(b * DIM + hh * HEAD_DIM + d)) * NPOS + n] = f2b(val);
      }
    }
  }
}

// ---------------- kernel 3: fused attention; in-register q scaling ----------------
__global__ __launch_bounds__(1024) void attn_kernel(
    const unsigned short* __restrict__ qT16, const unsigned short* __restrict__ kT16,
    const unsigned short* __restrict__ vb16, const float* __restrict__ sqk,
    const float* __restrict__ temp,
    const float* __restrict__ supp, const float* __restrict__ wpe,
    const float* __restrict__ bpe, unsigned short* __restrict__ ybT) {
  __shared__ __align__(128) unsigned short s16[16 * SSTRIDE]; // 51200 B, [qrow][m] bf16
  __shared__ unsigned short redb[16][2][16][18];              // PV partials bf16, padded
  __shared__ float pstat[2][16][16];                          // [stat][qrow][wave]
  __shared__ float dpart[16][16];                             // denom partials [n][wave]
  __shared__ float scal[16];
  int t = threadIdx.x, lane = t & 63, w = t >> 6;
  int l15 = lane & 15, lg = lane >> 4;
  int n0 = blockIdx.x * 16;
  int h = blockIdx.y, b = blockIdx.z;
  int bh = b * HEADS + h;
  float sgm = 1.0f / (1.0f + __expf(-supp[0]));

  // phase 0: per-kk scale = temp * invq * invk
  if (t < 16) {
    float a = sqk[bh * 16 + t];
    float bb = sqk[256 + bh * 16 + t];
    float invq = 1.0f / fmaxf(sqrtf(a), 1e-12f);
    float invk = 1.0f / fmaxf(sqrtf(bb), 1e-12f);
    scal[t] = temp[h] * invq * invk;
  }
  __syncthreads();

  // ---- phase 1: S^T = K*Q^T via mfma(K_frag, scaled Q_frag) ----
  {
    short8 qa = {0, 0, 0, 0, 0, 0, 0, 0};
    if (lane < 32) {
      short8 qr = *(const short8*)(qT16 + ((size_t)bh * NPOS + n0 + l15) * KEY_DIM + lg * 8);
      #pragma unroll
      for (int e = 0; e < 8; ++e)
        qa[e] = (short)f2b(b2f((unsigned short)qr[e]) * scal[lg * 8 + e]);
    }
    float ssum = 0.f, ssq = 0.f;
    for (int mt = w; mt < NPOS / 16; mt += 16) {
      int m0 = mt * 16;
      short8 kb = {0, 0, 0, 0, 0, 0, 0, 0};
      if (lane < 32)
        kb = *(const short8*)(kT16 + ((size_t)bh * NPOS + m0 + l15) * KEY_DIM + lg * 8);
      f32x4 acc = {0.f, 0.f, 0.f, 0.f};
      acc = __builtin_amdgcn_mfma_f32_16x16x32_bf16(kb, qa, acc, 0, 0, 0);
      short4v o;
      #pragma unroll
      for (int r = 0; r < 4; ++r) {
        float v = acc[r];
        o[r] = (short)f2b(v);
        ssum += v;
        ssq = fmaf(v, v, ssq);
      }
      int byteoff = (l15 * (SSTRIDE * 2) + (m0 + lg * 4) * 2) ^ smask(l15);
      *(short4v*)(s16 + (byteoff >> 1)) = o;
    }
    ssum += __shfl_xor(ssum, 16, 64); ssq += __shfl_xor(ssq, 16, 64);
    ssum += __shfl_xor(ssum, 32, 64); ssq += __shfl_xor(ssq, 32, 64);
    if (lane < 16) {
      pstat[0][l15][w] = ssum;
      pstat[1][l15][w] = ssq;
    }
  }
  __syncthreads();

  // ---- phase 2: wave w owns m-residue w; computes pb once, both d-tiles ----
  {
    float su = 0.f, sq = 0.f;
    #pragma unroll
    for (int j = 0; j < 4; ++j) {
      su += pstat[0][l15][lg + 4 * j];
      sq += pstat[1][l15][lg + 4 * j];
    }
    su += __shfl_xor(su, 16, 64); sq += __shfl_xor(sq, 16, 64);
    su += __shfl_xor(su, 32, 64); sq += __shfl_xor(sq, 32, 64);
    float mu = su * (1.0f / NPOS);
    float var = fmaxf(sq * (1.0f / NPOS) - mu * mu, 0.0f);
    float thr_lane = mu - 0.84162123f * sqrtf(var);   // 20th pctile (rank 320/1600)

    const unsigned short* vrow0 = vb16 + ((size_t)(b * DIM + h * HEAD_DIM + l15)) * NPOS;
    const unsigned short* vrow1 = vrow0 + (size_t)16 * NPOS;
    f32x4 acc0 = {0.f, 0.f, 0.f, 0.f};
    f32x4 acc1 = {0.f, 0.f, 0.f, 0.f};
    float psum = 0.0f;
    for (int c = w; c < NPOS / 32; c += 16) {
      int m0 = c * 32 + lg * 8;
      short8 va0 = *(const short8*)(vrow0 + m0);
      short8 va1 = *(const short8*)(vrow1 + m0);
      int byteoff = (l15 * (SSTRIDE * 2) + m0 * 2) ^ smask(l15);
      short8 sv = *(const short8*)(s16 + (byteoff >> 1));
      short8 pb;
      #pragma unroll
      for (int e = 0; e < 8; ++e) {
        float v = b2f((unsigned short)sv[e]);
        float p = (v >= thr_lane) ? v : v * sgm;
        float ex = 1.0f + p;
        psum += ex;
        pb[e] = (short)f2b(ex);
      }
      acc0 = __builtin_amdgcn_mfma_f32_16x16x32_bf16(va0, pb, acc0, 0, 0, 0);
      acc1 = __builtin_amdgcn_mfma_f32_16x16x32_bf16(va1, pb, acc1, 0, 0, 0);
    }
    psum += __shfl_xor(psum, 16, 64);
    psum += __shfl_xor(psum, 32, 64);
    if (lane < 16) dpart[l15][w] = psum;
    #pragma unroll
    for (int r = 0; r < 4; ++r) {
      redb[w][0][lg * 4 + r][l15] = f2b(acc0[r]);
      redb[w][1][lg * 4 + r][l15] = f2b(acc1[r]);
    }
  }
  __syncthreads();

  // ---- phase 3: 16-way cross-wave reduce + normalize + fused pe conv + bf16 store ----
  if (t < 512) {
    int tl = t >> 8, i = (t >> 4) & 15, j = t & 15;
    float v = 0.0f;
    #pragma unroll
    for (int s = 0; s < 16; ++s) v += b2f(redb[s][tl][i][j]);
    float den = 0.0f;
    #pragma unroll
    for (int s = 0; s < 16; ++s) den += dpart[j][s];
    int c = h * HEAD_DIM + tl * 16 + i;
    int n = n0 + j;
    float o = v / den;
    int py = n / 40, px = n - py * 40;
    const unsigned short* vp = vb16 + (size_t)(b * DIM + c) * NPOS;
    const float* w9 = wpe + c * 9;
    float acc2 = bpe[c];
    #pragma unroll
    for (int dy = -1; dy <= 1; ++dy) {
      int iy = py + dy;
      if (iy < 0 || iy > 39) continue;
      #pragma unroll
      for (int dx = -1; dx <= 1; ++dx) {
        int ix = px + dx;
        if (ix < 0 || ix > 39) continue;
        acc2 = fmaf(b2f(vp[iy * 40 + ix]), w9[(dy + 1) * 3 + (dx + 1)], acc2);
      }
    }
    o += acc2;
    ybT[((size_t)(b * NPOS + n)) * DIM + c] = f2b(o);
  }
}

// ---------------- kernel 5: proj via MFMA -> fp32 out ----------------
__global__ __launch_bounds__(256) void proj_mfma(
    const unsigned short* __restrict__ ybT, const unsigned short* __restrict__ wpb,
    const float* __restrict__ bp, float* __restrict__ out) {
  int t = threadIdx.x, lane = t & 63, w = t >> 6;
  int l15 = lane & 15, lg = lane >> 4;
  int n0 = blockIdx.x * 64, co0 = blockIdx.y * 64, b = blockIdx.z;
  int cow = co0 + w * 16;
  short8 af[8];
  #pragma unroll
  for (int ks = 0; ks < 8; ++ks)
    af[ks] = *(const short8*)(wpb + (size_t)(cow + l15) * DIM + ks * 32 + lg * 8);
  f32x4 acc[4];
  #pragma unroll
  for (int sub = 0; sub < 4; ++sub) {
    int n = n0 + sub * 16 + l15;
    const unsigned short* yb = ybT + (size_t)(b * NPOS + n) * DIM + lg * 8;
    f32x4 a = {0.f, 0.f, 0.f, 0.f};
    #pragma unroll
    for (int ks = 0; ks < 8; ++ks)
      a = __builtin_amdgcn_mfma_f32_16x16x32_bf16(af[ks], *(const short8*)(yb + ks * 32), a, 0, 0, 0);
    acc[sub] = a;
  }
  #pragma unroll
  for (int sub = 0; sub < 4; ++sub) {
    #pragma unroll
    for (int r = 0; r < 4; ++r) {
      int co = cow + lg * 4 + r;
      int n = n0 + sub * 16 + l15;
      out[((size_t)(b * DIM + co)) * NPOS + n] = acc[sub][r] + bp[co];
    }
  }
}

extern "C" void kernel_launch(void* const* d_in, const int* in_sizes, int n_in,
                              void* d_out, int out_size, void* d_ws, size_t ws_size,
                              hipStream_t stream) {
  (void)in_sizes; (void)n_in; (void)out_size; (void)ws_size;
  const float* x = (const float*)d_in[0];
  const float* w_qkv = (const float*)d_in[1];
  const float* b_qkv = (const float*)d_in[2];
  const float* w_proj = (const float*)d_in[3];
  const float* b_proj = (const float*)d_in[4];
  const float* w_pe = (const float*)d_in[5];
  const float* b_pe = (const float*)d_in[6];
  const float* temperature = (const float*)d_in[7];
  const float* supp = (const float*)d_in[8];

  unsigned short* wsu = (unsigned short*)d_ws;
  unsigned short* vb16 = wsu;                           // 819200 bf16
  unsigned short* qT16 = vb16 + 819200;                 // 409600
  unsigned short* kT16 = qT16 + 409600;                 // 409600
  unsigned short* ybT  = kT16 + 409600;                 // 819200
  unsigned short* wqb  = ybT + 819200;                  // 131072
  unsigned short* wpb  = wqb + 131072;                  // 65536
  float* sqk = (float*)(wpb + 65536);                   // 512 floats: q sumsq | k sumsq
  float* out = (float*)d_out;

  convw_kernel<<<dim3(96, 1, 1), 256, 0, stream>>>(w_qkv, w_proj, wqb, wpb, sqk);
  qkv_mfma<<<dim3(25, 8, 2), 256, 0, stream>>>(x, wqb, b_qkv, qT16, kT16, vb16, sqk);
  attn_kernel<<<dim3(NPOS / 16, HEADS, 2), 1024, 0, stream>>>(qT16, kT16, vb16, sqk, temperature, supp, w_pe, b_pe, ybT);
  proj_mfma<<<dim3(25, 4, 2), 256, 0, stream>>>(ybT, wpb, b_proj, out);
}